// Round 23
// baseline (101.490 us; speedup 1.0000x reference)
//
#include <hip/hip_runtime.h>
#include <hip/hip_bf16.h>
#include <math.h>

typedef _Float16 f16_t;
typedef _Float16 f16x4 __attribute__((ext_vector_type(4)));
typedef _Float16 f16x8 __attribute__((ext_vector_type(8)));
typedef float f32x4 __attribute__((ext_vector_type(4)));

#define BATCH 131072
#define MTILE 64               // rows per block (4 waves, 16 rows/wave)
#define NBLK (BATCH / MTILE)
#define LOG2E 1.4426950408889634f

// fragment-layout weight offsets in d_ws (elements, f16)
#define W1F 0
#define W2F 4096
#define W3F 20480
#define W4F 36864
#define B4S_OFF 67584          // float index into d_ws, 736 floats

// ---------------------------------------------------------------------------
// Kernel A: fp32 weights -> fp16 MFMA B-fragment layout.
//   col = tile*16 + (lane&15), k = kstep*32 + (lane>>4)*8 + j
// W4 laid out as 8 chunks x 92 cols padded to 96 (6 tiles).
// W4's softmax cols (col%23 < 16) pre-scaled by log2(e); b4 -> b4s likewise.
// ---------------------------------------------------------------------------
__global__ __launch_bounds__(256) void convert_weights_kernel(
    const float* __restrict__ W1, const float* __restrict__ W2,
    const float* __restrict__ W3, const float* __restrict__ W4,
    const float* __restrict__ b4, f16_t* __restrict__ wf,
    float* __restrict__ b4s) {
  int tid = blockIdx.x * 256 + threadIdx.x;
  if (tid >= 16896) {                    // tail: scale b4 -> b4s
    int i = tid - 16896;
    if (i < 736) {
      float s = ((i % 23) < 16) ? LOG2E : 1.f;
      b4s[i] = b4[i] * s;
    }
    return;
  }
  int lane = tid & 63;
  int l16 = lane & 15, lhi = lane >> 4;
  const float* W; int ncols, col, k0; bool zero = false; float scale = 1.f;
  if (tid < 512) {
    int n = tid >> 6;
    W = W1; ncols = 128; col = n * 16 + l16; k0 = lhi * 8;
  } else if (tid < 2560) {
    int g = tid - 512; int n = g >> 8, s = (g >> 6) & 3;
    W = W2; ncols = 128; col = n * 16 + l16; k0 = s * 32 + lhi * 8;
  } else if (tid < 4608) {
    int g = tid - 2560; int n = g >> 8, s = (g >> 6) & 3;
    W = W3; ncols = 128; col = n * 16 + l16; k0 = s * 32 + lhi * 8;
  } else {
    int g = tid - 4608; int t = g >> 8, s = (g >> 6) & 3;
    int c = t / 6, n = t - c * 6;
    int colc = n * 16 + l16;
    W = W4; ncols = 736; col = c * 92 + colc; k0 = s * 32 + lhi * 8;
    zero = (colc >= 92);
    if (!zero) scale = ((col % 23) < 16) ? LOG2E : 1.f;
  }
  f16x8 v;
#pragma unroll
  for (int j = 0; j < 8; ++j)
    v[j] = zero ? (f16_t)0.f : (f16_t)(W[(k0 + j) * ncols + col] * scale);
  *(f16x8*)(wf + (size_t)tid * 8) = v;
}

__device__ __forceinline__ float elu(float v) {
  return v > 0.f ? v : (__expf(v) - 1.f);
}

// cooperative linear stage: global -> LDS, 256 threads, coalesced 16B units
__device__ __forceinline__ void stage_w(f16_t* dst, const f16_t* __restrict__ src,
                                        int nelem, int tid) {
#pragma unroll
  for (int k = tid * 8; k < nelem; k += 2048)
    *(f16x8*)(dst + k) = *(const f16x8*)(src + k);
}

// ---------------------------------------------------------------------------
// spline for one (row, dim) task; P = 24-f16 param slot (16B-aligned).
// R18-validated lean form: exp2-domain softmax, deferred softplus,
// select-then-fma widths/heights, rcp divides, fused log.
// ---------------------------------------------------------------------------
__device__ __forceinline__ void rqs_task(const f16_t* P, float xv,
                                         float& yout, float& ldout) {
  f16x8 pw = *(const f16x8*)P;
  f16x8 ph = *(const f16x8*)(P + 8);
  f16x8 pd = *(const f16x8*)(P + 16);   // [7] is pad, unused

  float ew[8], sw = 0.f;
#pragma unroll
  for (int i = 0; i < 8; ++i) { ew[i] = exp2f((float)pw[i]); sw += ew[i]; }
  float invw = 0.992f * __builtin_amdgcn_rcpf(sw);
  float cw[8]; cw[0] = -3.f;
  float accw = 0.f;
#pragma unroll
  for (int i = 0; i < 7; ++i) {
    accw += 0.001f + ew[i] * invw;
    cw[i + 1] = -3.f + 6.f * accw;
  }

  float eh[8], sh = 0.f;
#pragma unroll
  for (int i = 0; i < 8; ++i) { eh[i] = exp2f((float)ph[i]); sh += eh[i]; }
  float invh = 0.992f * __builtin_amdgcn_rcpf(sh);
  float ch[8]; ch[0] = -3.f;
  float acch = 0.f;
#pragma unroll
  for (int i = 0; i < 7; ++i) {
    acch += 0.001f + eh[i] * invh;
    ch[i + 1] = -3.f + 6.f * acch;
  }

  float xc = fminf(fmaxf(xv, -3.f), 3.f);
  int bin = 0;
#pragma unroll
  for (int i = 1; i < 8; ++i) bin += (xc >= cw[i]) ? 1 : 0;

  float in_cw = cw[0], in_ch = ch[0];
  float ewsel = ew[0], ehsel = eh[0];
  float sd  = (float)pd[0];
  float sd1 = (float)pd[0];
#pragma unroll
  for (int i = 1; i < 8; ++i) {
    bool g = (bin >= i);
    in_cw = g ? cw[i] : in_cw;  in_ch = g ? ch[i] : in_ch;
    ewsel = g ? ew[i] : ewsel;  ehsel = g ? eh[i] : ehsel;
    sd    = g ? (float)pd[i - 1] : sd;
  }
#pragma unroll
  for (int i = 1; i < 7; ++i)
    sd1 = (bin >= i) ? (float)pd[i] : sd1;

  float in_w = fmaf(ewsel * invw, 6.f, 0.006f);
  float in_h = fmaf(ehsel * invh, 6.f, 0.006f);

  float spd  = fmaxf(sd,  0.f) + __logf(1.f + __expf(-fabsf(sd)));
  float spd1 = fmaxf(sd1, 0.f) + __logf(1.f + __expf(-fabsf(sd1)));
  float in_d  = (bin == 0) ? 1.f : 0.001f + spd;
  float in_d1 = (bin == 7) ? 1.f : 0.001f + spd1;

  float rw = __builtin_amdgcn_rcpf(in_w);
  float dlt = in_h * rw;
  float th = (xc - in_cw) * rw;
  float om = 1.f - th;
  float t1 = th * om;
  float num = in_h * (dlt * th * th + in_d * t1);
  float den = dlt + (in_d + in_d1 - 2.f * dlt) * t1;
  float rden = __builtin_amdgcn_rcpf(den);
  float yo = in_ch + num * rden;
  float dn = dlt * dlt * (in_d1 * th * th + 2.f * dlt * t1 + in_d * om * om);
  float ldv = __logf(dn * rden * rden);
  bool inside = (xv >= -3.f) && (xv <= 3.f);
  yout = inside ? yo : xv;
  ldout = inside ? ldv : 0.f;
}

// ---------------------------------------------------------------------------
// half of a middle MLP layer from the LDS weight buffer (4 n-tiles).
// A-fragments must already be register-resident (caller loads them).
// ---------------------------------------------------------------------------
__device__ __forceinline__ void mid_half(f16_t* hH, const f16_t* wL,
                                         const float* __restrict__ bg,
                                         int nbase, const f16x8 a[4],
                                         int wv, int l16, int lhi, int lane) {
#pragma unroll
  for (int nl = 0; nl < 4; ++nl) {
    f32x4 acc = {0.f, 0.f, 0.f, 0.f};
#pragma unroll
    for (int s = 0; s < 4; ++s) {
      f16x8 b = *(const f16x8*)(wL + (size_t)((nl * 4 + s) * 64 + lane) * 8);
      acc = __builtin_amdgcn_mfma_f32_16x16x32_f16(a[s], b, acc, 0, 0, 0);
    }
    int n = nbase + nl;
    float bias = bg[n * 16 + l16];
#pragma unroll
    for (int r = 0; r < 4; ++r)
      hH[(wv * 16 + lhi * 4 + r) * 136 + n * 16 + l16] =
          (f16_t)elu(acc[r] + bias);
  }
}

// ---------------------------------------------------------------------------
// Kernel B: R21 structure + BLOCK-SHARED LDS WEIGHT STAGING.
// Each weight segment is loaded from L2 ONCE PER BLOCK (not once per wave):
// L2 weight traffic drops 4x (2.16 GB -> 540 MB per launch). B-fragments
// become conflict-free ds_read_b128. prm aliases dead hH (R21-proven).
// LDS: 17408 (hH/prm) + 16384 (wL) + 4096 (x2s f16) = 37888 B -> 4 blk/CU.
// ---------------------------------------------------------------------------
__global__ __launch_bounds__(256, 4) void nsf_fused_kernel(
    const float* __restrict__ x,
    const float* __restrict__ b1g, const float* __restrict__ b2g,
    const float* __restrict__ b3g, const float* __restrict__ b4s,
    const f16_t* __restrict__ wf,
    float* __restrict__ out) {
  __shared__ f16_t hH[MTILE * 136];   // hidden state; becomes prm after a4 hoist
  __shared__ f16_t wL[8192];          // staged weight segment (16 KB)
  __shared__ f16_t x2s[MTILE * 32];   // x2 tile, f16

  const int tid = threadIdx.x;
  const int lane = tid & 63;
  const int wv = tid >> 6;
  const int l16 = lane & 15, lhi = lane >> 4;
  const int row0 = blockIdx.x * MTILE;

  // ---- stage x: x1 -> out + hH (f16), x2 -> x2s (f16) ----
  {
    const float4* x4 = (const float4*)(x + (size_t)row0 * 64);
    float4* o4 = (float4*)(out + (size_t)row0 * 64);
#pragma unroll
    for (int it = 0; it < 4; ++it) {
      int idx = tid + it * 256;          // 0..1023 = 64 rows x 16 float4
      int row = idx >> 4, q = idx & 15;
      float4 v = x4[row * 16 + q];
      f16x4 p = {(f16_t)v.x, (f16_t)v.y, (f16_t)v.z, (f16_t)v.w};
      if (q < 8) {                       // x1 cols 0..31
        o4[row * 16 + q] = v;
        *(f16x4*)&hH[row * 136 + q * 4] = p;
      } else {                           // x2 cols 32..63
        *(f16x4*)&x2s[row * 32 + (q - 8) * 4] = p;
      }
    }
  }
  // stage W1 into wL (4096 f16); sync covers both x-stage and W1-stage
  stage_w(wL, wf + W1F, 4096, tid);
  __syncthreads();

  // ---- layer 1: (64x32)@(32x128), K=32, in-place, B from LDS ----
  {
    f16x8 a = *(const f16x8*)&hH[(wv * 16 + l16) * 136 + lhi * 8];
#pragma unroll
    for (int n = 0; n < 8; ++n) {
      f16x8 b = *(const f16x8*)(wL + (size_t)(n * 64 + lane) * 8);
      f32x4 acc = {0.f, 0.f, 0.f, 0.f};
      acc = __builtin_amdgcn_mfma_f32_16x16x32_f16(a, b, acc, 0, 0, 0);
      float bias = b1g[n * 16 + l16];
#pragma unroll
      for (int r = 0; r < 4; ++r)
        hH[(wv * 16 + lhi * 4 + r) * 136 + n * 16 + l16] =
            (f16_t)elu(acc[r] + bias);
    }
  }
  __syncthreads();

  // ---- layers 2 and 3: staged in 2 halves of 8192 f16 each ----
#pragma unroll
  for (int L = 0; L < 2; ++L) {
    const f16_t* wseg = wf + (L ? W3F : W2F);
    const float* bg = L ? b3g : b2g;
    f16x8 a[4];                          // load A BEFORE any store this layer
#pragma unroll
    for (int s = 0; s < 4; ++s)
      a[s] = *(const f16x8*)&hH[(wv * 16 + l16) * 136 + s * 32 + lhi * 8];
    stage_w(wL, wseg, 8192, tid);
    __syncthreads();
    mid_half(hH, wL, bg, 0, a, wv, l16, lhi, lane);   // n = 0..3
    __syncthreads();                     // all wL reads done
    stage_w(wL, wseg + 8192, 8192, tid);
    __syncthreads();
    mid_half(hH, wL, bg, 4, a, wv, l16, lhi, lane);   // n = 4..7
    __syncthreads();
  }

  // ---- layer 4 + spline; prm aliases the (now dead) hH ----
  {
    f16x8 a4[4];
#pragma unroll
    for (int s = 0; s < 4; ++s)
      a4[s] = *(const f16x8*)&hH[(wv * 16 + l16) * 136 + s * 32 + lhi * 8];
    __syncthreads();   // ALL waves' a4 in registers -> hH region retired

    const int srow = tid >> 2;   // spline row 0..63 (== wave's own rows)
    const int sjj = tid & 3;     // chunk-local spline dim
    float ldp = 0.f;

    for (int c = 0; c < 8; ++c) {
      // ---- part A: n-tiles 0..3 (colc 0..63, always < 92) ----
      stage_w(wL, wf + W4F + (size_t)c * 12288, 8192, tid);
      __syncthreads();
#pragma unroll
      for (int nl = 0; nl < 4; ++nl) {
        f32x4 acc = {0.f, 0.f, 0.f, 0.f};
#pragma unroll
        for (int s = 0; s < 4; ++s) {
          f16x8 b = *(const f16x8*)(wL + (size_t)((nl * 4 + s) * 64 + lane) * 8);
          acc = __builtin_amdgcn_mfma_f32_16x16x32_f16(a4[s], b, acc, 0, 0, 0);
        }
        int colc = nl * 16 + l16;
        int dm = (colc * 90) >> 11;          // colc / 23 for colc < 92
        int j = colc - dm * 23;
        float bias = b4s[c * 92 + colc];
#pragma unroll
        for (int r = 0; r < 4; ++r)
          hH[((wv * 16 + lhi * 4 + r) * 4 + dm) * 24 + j] =
              (f16_t)(acc[r] + bias);
      }
      __syncthreads();                     // wL reads done

      // ---- part B: n-tiles 4..5 (colc 64..95, guard < 92) ----
      stage_w(wL, wf + W4F + (size_t)c * 12288 + 8192, 4096, tid);
      __syncthreads();
#pragma unroll
      for (int nl = 0; nl < 2; ++nl) {
        f32x4 acc = {0.f, 0.f, 0.f, 0.f};
#pragma unroll
        for (int s = 0; s < 4; ++s) {
          f16x8 b = *(const f16x8*)(wL + (size_t)((nl * 4 + s) * 64 + lane) * 8);
          acc = __builtin_amdgcn_mfma_f32_16x16x32_f16(a4[s], b, acc, 0, 0, 0);
        }
        int colc = (4 + nl) * 16 + l16;
        if (colc < 92) {
          int dm = (colc * 90) >> 11;
          int j = colc - dm * 23;
          float bias = b4s[c * 92 + colc];
#pragma unroll
          for (int r = 0; r < 4; ++r)
            hH[((wv * 16 + lhi * 4 + r) * 4 + dm) * 24 + j] =
                (f16_t)(acc[r] + bias);
        }
      }
      __builtin_amdgcn_wave_barrier();     // prm writer==reader wave

      // ---- spline: one (row, dim) task per thread (slot == tid) ----
      {
        int jg = c * 4 + sjj;
        float xv = (float)x2s[srow * 32 + jg];
        float y0, l0;
        rqs_task(hH + tid * 24, xv, y0, l0);
        out[(size_t)(row0 + srow) * 64 + 32 + jg] = y0;
        ldp += l0;
      }
      __syncthreads();                     // WAR: prm + wL before next chunk
    }

    // ---- log_det: quad reduce over sjj ----
    ldp += __shfl_xor(ldp, 1, 64);
    ldp += __shfl_xor(ldp, 2, 64);
    if ((tid & 3) == 0)
      out[(size_t)BATCH * 64 + row0 + srow] = ldp;
  }
}

// ---------------------------------------------------------------------------
extern "C" void kernel_launch(void* const* d_in, const int* in_sizes, int n_in,
                              void* d_out, int out_size, void* d_ws, size_t ws_size,
                              hipStream_t stream) {
  const float* x  = (const float*)d_in[0];
  const float* W1 = (const float*)d_in[1];
  const float* b1 = (const float*)d_in[2];
  const float* W2 = (const float*)d_in[3];
  const float* b2 = (const float*)d_in[4];
  const float* W3 = (const float*)d_in[5];
  const float* b3 = (const float*)d_in[6];
  const float* W4 = (const float*)d_in[7];
  const float* b4 = (const float*)d_in[8];
  f16_t* wf = (f16_t*)d_ws;
  float* b4s = (float*)d_ws + B4S_OFF;
  float* out = (float*)d_out;

  hipLaunchKernelGGL(convert_weights_kernel, dim3(69), dim3(256), 0, stream,
                     W1, W2, W3, W4, b4, wf, b4s);
  hipLaunchKernelGGL(nsf_fused_kernel, dim3(NBLK), dim3(256), 0, stream,
                     x, b1, b2, b3, b4s, wf, out);
}

// Round 24
// 101.305 us; speedup vs baseline: 1.0018x; 1.0018x over previous
//
#include <hip/hip_runtime.h>
#include <hip/hip_bf16.h>
#include <math.h>

typedef _Float16 f16_t;
typedef _Float16 f16x4 __attribute__((ext_vector_type(4)));
typedef _Float16 f16x8 __attribute__((ext_vector_type(8)));
typedef float f32x4 __attribute__((ext_vector_type(4)));

#define BATCH 131072
#define MTILE 16               // rows per block (ONE wave)
#define NBLK (BATCH / MTILE)   // 8192 blocks
#define LOG2E 1.4426950408889634f

// fragment-layout weight offsets in d_ws (elements, f16)
#define W1F 0
#define W2F 4096
#define W3F 20480
#define W4F 36864
#define B4S_OFF 67584          // float index into d_ws, 736 floats

// ---------------------------------------------------------------------------
// Kernel A: fp32 weights -> fp16 MFMA B-fragment layout.
//   col = tile*16 + (lane&15), k = kstep*32 + (lane>>4)*8 + j
// W4 laid out as 8 chunks x 92 cols padded to 96 (6 tiles).
// W4's softmax cols (col%23 < 16) pre-scaled by log2(e); b4 -> b4s likewise.
// ---------------------------------------------------------------------------
__global__ __launch_bounds__(256) void convert_weights_kernel(
    const float* __restrict__ W1, const float* __restrict__ W2,
    const float* __restrict__ W3, const float* __restrict__ W4,
    const float* __restrict__ b4, f16_t* __restrict__ wf,
    float* __restrict__ b4s) {
  int tid = blockIdx.x * 256 + threadIdx.x;
  if (tid >= 16896) {                    // tail: scale b4 -> b4s
    int i = tid - 16896;
    if (i < 736) {
      float s = ((i % 23) < 16) ? LOG2E : 1.f;
      b4s[i] = b4[i] * s;
    }
    return;
  }
  int lane = tid & 63;
  int l16 = lane & 15, lhi = lane >> 4;
  const float* W; int ncols, col, k0; bool zero = false; float scale = 1.f;
  if (tid < 512) {
    int n = tid >> 6;
    W = W1; ncols = 128; col = n * 16 + l16; k0 = lhi * 8;
  } else if (tid < 2560) {
    int g = tid - 512; int n = g >> 8, s = (g >> 6) & 3;
    W = W2; ncols = 128; col = n * 16 + l16; k0 = s * 32 + lhi * 8;
  } else if (tid < 4608) {
    int g = tid - 2560; int n = g >> 8, s = (g >> 6) & 3;
    W = W3; ncols = 128; col = n * 16 + l16; k0 = s * 32 + lhi * 8;
  } else {
    int g = tid - 4608; int t = g >> 8, s = (g >> 6) & 3;
    int c = t / 6, n = t - c * 6;
    int colc = n * 16 + l16;
    W = W4; ncols = 736; col = c * 92 + colc; k0 = s * 32 + lhi * 8;
    zero = (colc >= 92);
    if (!zero) scale = ((col % 23) < 16) ? LOG2E : 1.f;
  }
  f16x8 v;
#pragma unroll
  for (int j = 0; j < 8; ++j)
    v[j] = zero ? (f16_t)0.f : (f16_t)(W[(k0 + j) * ncols + col] * scale);
  *(f16x8*)(wf + (size_t)tid * 8) = v;
}

__device__ __forceinline__ float elu(float v) {
  return v > 0.f ? v : (__expf(v) - 1.f);
}

// ---------------------------------------------------------------------------
// spline for one (row, dim) task; P = 24-f16 param slot (16B-aligned).
// R18-validated lean form: exp2-domain softmax, deferred softplus,
// select-then-fma widths/heights, rcp divides, fused log.
// ---------------------------------------------------------------------------
__device__ __forceinline__ void rqs_task(const f16_t* P, float xv,
                                         float& yout, float& ldout) {
  f16x8 pw = *(const f16x8*)P;
  f16x8 ph = *(const f16x8*)(P + 8);
  f16x8 pd = *(const f16x8*)(P + 16);   // [7] is pad, unused

  float ew[8], sw = 0.f;
#pragma unroll
  for (int i = 0; i < 8; ++i) { ew[i] = exp2f((float)pw[i]); sw += ew[i]; }
  float invw = 0.992f * __builtin_amdgcn_rcpf(sw);
  float cw[8]; cw[0] = -3.f;
  float accw = 0.f;
#pragma unroll
  for (int i = 0; i < 7; ++i) {
    accw += 0.001f + ew[i] * invw;
    cw[i + 1] = -3.f + 6.f * accw;
  }

  float eh[8], sh = 0.f;
#pragma unroll
  for (int i = 0; i < 8; ++i) { eh[i] = exp2f((float)ph[i]); sh += eh[i]; }
  float invh = 0.992f * __builtin_amdgcn_rcpf(sh);
  float ch[8]; ch[0] = -3.f;
  float acch = 0.f;
#pragma unroll
  for (int i = 0; i < 7; ++i) {
    acch += 0.001f + eh[i] * invh;
    ch[i + 1] = -3.f + 6.f * acch;
  }

  float xc = fminf(fmaxf(xv, -3.f), 3.f);
  int bin = 0;
#pragma unroll
  for (int i = 1; i < 8; ++i) bin += (xc >= cw[i]) ? 1 : 0;

  float in_cw = cw[0], in_ch = ch[0];
  float ewsel = ew[0], ehsel = eh[0];
  float sd  = (float)pd[0];
  float sd1 = (float)pd[0];
#pragma unroll
  for (int i = 1; i < 8; ++i) {
    bool g = (bin >= i);
    in_cw = g ? cw[i] : in_cw;  in_ch = g ? ch[i] : in_ch;
    ewsel = g ? ew[i] : ewsel;  ehsel = g ? eh[i] : ehsel;
    sd    = g ? (float)pd[i - 1] : sd;
  }
#pragma unroll
  for (int i = 1; i < 7; ++i)
    sd1 = (bin >= i) ? (float)pd[i] : sd1;

  float in_w = fmaf(ewsel * invw, 6.f, 0.006f);
  float in_h = fmaf(ehsel * invh, 6.f, 0.006f);

  float spd  = fmaxf(sd,  0.f) + __logf(1.f + __expf(-fabsf(sd)));
  float spd1 = fmaxf(sd1, 0.f) + __logf(1.f + __expf(-fabsf(sd1)));
  float in_d  = (bin == 0) ? 1.f : 0.001f + spd;
  float in_d1 = (bin == 7) ? 1.f : 0.001f + spd1;

  float rw = __builtin_amdgcn_rcpf(in_w);
  float dlt = in_h * rw;
  float th = (xc - in_cw) * rw;
  float om = 1.f - th;
  float t1 = th * om;
  float num = in_h * (dlt * th * th + in_d * t1);
  float den = dlt + (in_d + in_d1 - 2.f * dlt) * t1;
  float rden = __builtin_amdgcn_rcpf(den);
  float yo = in_ch + num * rden;
  float dn = dlt * dlt * (in_d1 * th * th + 2.f * dlt * t1 + in_d * om * om);
  float ldv = __logf(dn * rden * rden);
  bool inside = (xv >= -3.f) && (xv <= 3.f);
  yout = inside ? yo : xv;
  ldout = inside ? ldv : 0.f;
}

// ---------------------------------------------------------------------------
// middle MLP layer: in-place on the block's (= wave's) 16-row hH.
// A-fragments are register-resident before the first store.
// ---------------------------------------------------------------------------
__device__ __forceinline__ void mid_layer_ip(f16_t* hH,
                                             const f16_t* __restrict__ wseg,
                                             const float* __restrict__ bg,
                                             int l16, int lhi, int lane) {
  f16x8 a[4];
#pragma unroll
  for (int s = 0; s < 4; ++s)
    a[s] = *(const f16x8*)&hH[l16 * 136 + s * 32 + lhi * 8];
#pragma unroll
  for (int n = 0; n < 8; ++n) {
    f32x4 acc = {0.f, 0.f, 0.f, 0.f};
#pragma unroll
    for (int s = 0; s < 4; ++s) {
      f16x8 b = *(const f16x8*)(wseg + (size_t)((n * 4 + s) * 64 + lane) * 8);
      acc = __builtin_amdgcn_mfma_f32_16x16x32_f16(a[s], b, acc, 0, 0, 0);
    }
    float bias = bg[n * 16 + l16];
#pragma unroll
    for (int r = 0; r < 4; ++r)
      hH[(lhi * 4 + r) * 136 + n * 16 + l16] = (f16_t)elu(acc[r] + bias);
  }
}

// ---------------------------------------------------------------------------
// Kernel B: ONE WAVE PER BLOCK (16 rows). Everything wave-private -> zero
// block barriers; wave_barrier for LDS ordering (R20-proven). LDS/block =
// 4352 (hH, prm-aliased) + 2112 (x2s fp32) = 6464 B -> ~24 blocks/CU
// permitted; no launch_bounds min-wave constraint, full ~60-VGPR waves.
// Tests the last untested quadrant: high occupancy x full registers.
// ---------------------------------------------------------------------------
__global__ __launch_bounds__(64) void nsf_fused_kernel(
    const float* __restrict__ x,
    const float* __restrict__ b1g, const float* __restrict__ b2g,
    const float* __restrict__ b3g, const float* __restrict__ b4s,
    const f16_t* __restrict__ wf,
    float* __restrict__ out) {
  __shared__ f16_t hH[MTILE * 136];   // hidden state; becomes prm after a4 hoist
  __shared__ float x2s[MTILE * 33];   // x2 tile, fp32

  const int lane = threadIdx.x;       // 0..63
  const int l16 = lane & 15, lhi = lane >> 4;
  const int row0 = blockIdx.x * MTILE;

  // ---- stage x: x1 -> out + hH (f16), x2 -> x2s (f32) ----
  {
    const float4* x4 = (const float4*)(x + (size_t)row0 * 64);
    float4* o4 = (float4*)(out + (size_t)row0 * 64);
#pragma unroll
    for (int i = 0; i < 4; ++i) {
      int flat = i * 64 + lane;          // 0..255 = 16 rows x 16 float4
      int r = flat >> 4, f = flat & 15;
      float4 v = x4[r * 16 + f];
      if (f < 8) {                       // x1 cols 0..31
        o4[r * 16 + f] = v;
        f16x4 p = {(f16_t)v.x, (f16_t)v.y, (f16_t)v.z, (f16_t)v.w};
        *(f16x4*)&hH[r * 136 + f * 4] = p;
      } else {                           // x2 cols 32..63
        int cb = r * 33 + (f - 8) * 4;
        x2s[cb + 0] = v.x; x2s[cb + 1] = v.y;
        x2s[cb + 2] = v.z; x2s[cb + 3] = v.w;
      }
    }
  }
  __builtin_amdgcn_wave_barrier();

  // ---- layer 1: (16x32)@(32x128), K=32, in-place ----
  {
    f16x8 a = *(const f16x8*)&hH[l16 * 136 + lhi * 8];
#pragma unroll
    for (int n = 0; n < 8; ++n) {
      f16x8 b = *(const f16x8*)(wf + W1F + (size_t)(n * 64 + lane) * 8);
      f32x4 acc = {0.f, 0.f, 0.f, 0.f};
      acc = __builtin_amdgcn_mfma_f32_16x16x32_f16(a, b, acc, 0, 0, 0);
      float bias = b1g[n * 16 + l16];
#pragma unroll
      for (int r = 0; r < 4; ++r)
        hH[(lhi * 4 + r) * 136 + n * 16 + l16] = (f16_t)elu(acc[r] + bias);
    }
  }
  __builtin_amdgcn_wave_barrier();

  mid_layer_ip(hH, wf + W2F, b2g, l16, lhi, lane);   // layer 2
  __builtin_amdgcn_wave_barrier();
  mid_layer_ip(hH, wf + W3F, b3g, l16, lhi, lane);   // layer 3
  __builtin_amdgcn_wave_barrier();

  // ---- layer 4 + spline; prm aliases the (now dead) hH ----
  {
    f16x8 a4[4];
#pragma unroll
    for (int s = 0; s < 4; ++s)
      a4[s] = *(const f16x8*)&hH[l16 * 136 + s * 32 + lhi * 8];
    __builtin_amdgcn_wave_barrier();   // a4 in registers -> hH retired

    const int srow = lane >> 2;   // spline row 0..15
    const int sjj = lane & 3;     // chunk-local spline dim
    float ldp = 0.f;

    for (int c = 0; c < 8; ++c) {
      // GEMM4 chunk: 92 real cols (4 dims x 23) padded to 96 (6 tiles)
#pragma unroll
      for (int n = 0; n < 6; ++n) {
        f32x4 acc = {0.f, 0.f, 0.f, 0.f};
#pragma unroll
        for (int s = 0; s < 4; ++s) {
          f16x8 b = *(const f16x8*)(wf + W4F +
                      (size_t)(((c * 6 + n) * 4 + s) * 64 + lane) * 8);
          acc = __builtin_amdgcn_mfma_f32_16x16x32_f16(a4[s], b, acc, 0, 0, 0);
        }
        int colc = n * 16 + l16;
        if (colc < 92) {
          int dm = (colc * 90) >> 11;          // colc / 23 for colc < 92
          int j = colc - dm * 23;
          float bias = b4s[c * 92 + colc];
#pragma unroll
          for (int r = 0; r < 4; ++r)
            hH[((lhi * 4 + r) * 4 + dm) * 24 + j] = (f16_t)(acc[r] + bias);
        }
      }
      __builtin_amdgcn_wave_barrier();     // write -> read, same wave

      // ---- spline: one (row, dim) task per thread (slot == lane) ----
      {
        int jg = c * 4 + sjj;
        float xv = x2s[srow * 33 + jg];
        float y0, l0;
        rqs_task(hH + lane * 24, xv, y0, l0);
        out[(size_t)(row0 + srow) * 64 + 32 + jg] = y0;
        ldp += l0;
      }
      __builtin_amdgcn_wave_barrier();     // WAR before next chunk's writes
    }

    // ---- log_det: quad reduce over sjj ----
    ldp += __shfl_xor(ldp, 1, 64);
    ldp += __shfl_xor(ldp, 2, 64);
    if ((lane & 3) == 0)
      out[(size_t)BATCH * 64 + row0 + srow] = ldp;
  }
}

// ---------------------------------------------------------------------------
extern "C" void kernel_launch(void* const* d_in, const int* in_sizes, int n_in,
                              void* d_out, int out_size, void* d_ws, size_t ws_size,
                              hipStream_t stream) {
  const float* x  = (const float*)d_in[0];
  const float* W1 = (const float*)d_in[1];
  const float* b1 = (const float*)d_in[2];
  const float* W2 = (const float*)d_in[3];
  const float* b2 = (const float*)d_in[4];
  const float* W3 = (const float*)d_in[5];
  const float* b3 = (const float*)d_in[6];
  const float* W4 = (const float*)d_in[7];
  const float* b4 = (const float*)d_in[8];
  f16_t* wf = (f16_t*)d_ws;
  float* b4s = (float*)d_ws + B4S_OFF;
  float* out = (float*)d_out;

  hipLaunchKernelGGL(convert_weights_kernel, dim3(69), dim3(256), 0, stream,
                     W1, W2, W3, W4, b4, wf, b4s);
  hipLaunchKernelGGL(nsf_fused_kernel, dim3(NBLK), dim3(64), 0, stream,
                     x, b1, b2, b3, b4s, wf, out);
}

// Round 26
// 97.715 us; speedup vs baseline: 1.0386x; 1.0367x over previous
//
#include <hip/hip_runtime.h>
#include <hip/hip_bf16.h>
#include <math.h>

typedef _Float16 f16_t;
typedef _Float16 f16x4 __attribute__((ext_vector_type(4)));
typedef _Float16 f16x8 __attribute__((ext_vector_type(8)));
typedef float f32x4 __attribute__((ext_vector_type(4)));

#define BATCH 131072
#define MTILE 64               // rows per block (4 waves, 16 rows/wave)
#define NBLK (BATCH / MTILE)
#define LOG2E 1.4426950408889634f

// fragment-layout weight offsets in d_ws (elements, f16)
#define W1F 0
#define W2F 4096
#define W3F 20480
#define W4F 36864
#define B4S_OFF 67584          // float index into d_ws, 736 floats

// ---------------------------------------------------------------------------
// Kernel A: fp32 weights -> fp16 MFMA B-fragment layout.
//   col = tile*16 + (lane&15), k = kstep*32 + (lane>>4)*8 + j
// W4 laid out as 8 chunks x 92 cols padded to 96 (6 tiles).
// W4's softmax cols (col%23 < 16) pre-scaled by log2(e); b4 -> b4s likewise.
// ---------------------------------------------------------------------------
__global__ __launch_bounds__(256) void convert_weights_kernel(
    const float* __restrict__ W1, const float* __restrict__ W2,
    const float* __restrict__ W3, const float* __restrict__ W4,
    const float* __restrict__ b4, f16_t* __restrict__ wf,
    float* __restrict__ b4s) {
  int tid = blockIdx.x * 256 + threadIdx.x;
  if (tid >= 16896) {                    // tail: scale b4 -> b4s
    int i = tid - 16896;
    if (i < 736) {
      float s = ((i % 23) < 16) ? LOG2E : 1.f;
      b4s[i] = b4[i] * s;
    }
    return;
  }
  int lane = tid & 63;
  int l16 = lane & 15, lhi = lane >> 4;
  const float* W; int ncols, col, k0; bool zero = false; float scale = 1.f;
  if (tid < 512) {
    int n = tid >> 6;
    W = W1; ncols = 128; col = n * 16 + l16; k0 = lhi * 8;
  } else if (tid < 2560) {
    int g = tid - 512; int n = g >> 8, s = (g >> 6) & 3;
    W = W2; ncols = 128; col = n * 16 + l16; k0 = s * 32 + lhi * 8;
  } else if (tid < 4608) {
    int g = tid - 2560; int n = g >> 8, s = (g >> 6) & 3;
    W = W3; ncols = 128; col = n * 16 + l16; k0 = s * 32 + lhi * 8;
  } else {
    int g = tid - 4608; int t = g >> 8, s = (g >> 6) & 3;
    int c = t / 6, n = t - c * 6;
    int colc = n * 16 + l16;
    W = W4; ncols = 736; col = c * 92 + colc; k0 = s * 32 + lhi * 8;
    zero = (colc >= 92);
    if (!zero) scale = ((col % 23) < 16) ? LOG2E : 1.f;
  }
  f16x8 v;
#pragma unroll
  for (int j = 0; j < 8; ++j)
    v[j] = zero ? (f16_t)0.f : (f16_t)(W[(k0 + j) * ncols + col] * scale);
  *(f16x8*)(wf + (size_t)tid * 8) = v;
}

__device__ __forceinline__ float elu(float v) {
  return v > 0.f ? v : (__expf(v) - 1.f);
}

// ---------------------------------------------------------------------------
// spline for one (row, dim) task; P = 24-f16 param slot (16B-aligned).
// R18-validated lean form: exp2-domain softmax, deferred softplus,
// select-then-fma widths/heights, rcp divides, fused log.
// ---------------------------------------------------------------------------
__device__ __forceinline__ void rqs_task(const f16_t* P, float xv,
                                         float& yout, float& ldout) {
  f16x8 pw = *(const f16x8*)P;
  f16x8 ph = *(const f16x8*)(P + 8);
  f16x8 pd = *(const f16x8*)(P + 16);   // [7] is pad, unused

  float ew[8], sw = 0.f;
#pragma unroll
  for (int i = 0; i < 8; ++i) { ew[i] = exp2f((float)pw[i]); sw += ew[i]; }
  float invw = 0.992f * __builtin_amdgcn_rcpf(sw);
  float cw[8]; cw[0] = -3.f;
  float accw = 0.f;
#pragma unroll
  for (int i = 0; i < 7; ++i) {
    accw += 0.001f + ew[i] * invw;
    cw[i + 1] = -3.f + 6.f * accw;
  }

  float eh[8], sh = 0.f;
#pragma unroll
  for (int i = 0; i < 8; ++i) { eh[i] = exp2f((float)ph[i]); sh += eh[i]; }
  float invh = 0.992f * __builtin_amdgcn_rcpf(sh);
  float ch[8]; ch[0] = -3.f;
  float acch = 0.f;
#pragma unroll
  for (int i = 0; i < 7; ++i) {
    acch += 0.001f + eh[i] * invh;
    ch[i + 1] = -3.f + 6.f * acch;
  }

  float xc = fminf(fmaxf(xv, -3.f), 3.f);
  int bin = 0;
#pragma unroll
  for (int i = 1; i < 8; ++i) bin += (xc >= cw[i]) ? 1 : 0;

  float in_cw = cw[0], in_ch = ch[0];
  float ewsel = ew[0], ehsel = eh[0];
  float sd  = (float)pd[0];
  float sd1 = (float)pd[0];
#pragma unroll
  for (int i = 1; i < 8; ++i) {
    bool g = (bin >= i);
    in_cw = g ? cw[i] : in_cw;  in_ch = g ? ch[i] : in_ch;
    ewsel = g ? ew[i] : ewsel;  ehsel = g ? eh[i] : ehsel;
    sd    = g ? (float)pd[i - 1] : sd;
  }
#pragma unroll
  for (int i = 1; i < 7; ++i)
    sd1 = (bin >= i) ? (float)pd[i] : sd1;

  float in_w = fmaf(ewsel * invw, 6.f, 0.006f);
  float in_h = fmaf(ehsel * invh, 6.f, 0.006f);

  float spd  = fmaxf(sd,  0.f) + __logf(1.f + __expf(-fabsf(sd)));
  float spd1 = fmaxf(sd1, 0.f) + __logf(1.f + __expf(-fabsf(sd1)));
  float in_d  = (bin == 0) ? 1.f : 0.001f + spd;
  float in_d1 = (bin == 7) ? 1.f : 0.001f + spd1;

  float rw = __builtin_amdgcn_rcpf(in_w);
  float dlt = in_h * rw;
  float th = (xc - in_cw) * rw;
  float om = 1.f - th;
  float t1 = th * om;
  float num = in_h * (dlt * th * th + in_d * t1);
  float den = dlt + (in_d + in_d1 - 2.f * dlt) * t1;
  float rden = __builtin_amdgcn_rcpf(den);
  float yo = in_ch + num * rden;
  float dn = dlt * dlt * (in_d1 * th * th + 2.f * dlt * t1 + in_d * om * om);
  float ldv = __logf(dn * rden * rden);
  bool inside = (xv >= -3.f) && (xv <= 3.f);
  yout = inside ? yo : xv;
  ldout = inside ? ldv : 0.f;
}

// ---------------------------------------------------------------------------
// middle MLP layer (R13 form): in-place on the wave's 16-row strip of hH.
// ---------------------------------------------------------------------------
__device__ __forceinline__ void mid_layer_ip(f16_t* hH,
                                             const f16_t* __restrict__ wseg,
                                             const float* __restrict__ bg,
                                             int wv, int l16, int lhi, int lane) {
  f16x8 a[4];
#pragma unroll
  for (int s = 0; s < 4; ++s)
    a[s] = *(const f16x8*)&hH[(wv * 16 + l16) * 136 + s * 32 + lhi * 8];
#pragma unroll
  for (int n = 0; n < 8; ++n) {
    f32x4 acc = {0.f, 0.f, 0.f, 0.f};
#pragma unroll
    for (int s = 0; s < 4; ++s) {
      f16x8 b = *(const f16x8*)(wseg + (size_t)((n * 4 + s) * 64 + lane) * 8);
      acc = __builtin_amdgcn_mfma_f32_16x16x32_f16(a[s], b, acc, 0, 0, 0);
    }
    float bias = bg[n * 16 + l16];
#pragma unroll
    for (int r = 0; r < 4; ++r)
      hH[(wv * 16 + lhi * 4 + r) * 136 + n * 16 + l16] =
          (f16_t)elu(acc[r] + bias);
  }
}

// ---------------------------------------------------------------------------
// Kernel B: the R20 plateau kernel (best validated: 97.66 us, absmax 0.625).
// R18 structure with chunk-loop barriers relaxed to wave_barrier (prm is
// wave-local: GEMM4 of wave w writes slots [64w,64w+64); spline reader of
// slot s is thread tid==s — same wave). Stage/layer barriers block-wide.
// LDS: 17408 (hH) + 12288 (prm) + 8448 (x2s) = 38144 B -> 4 blocks/CU.
// ---------------------------------------------------------------------------
__global__ __launch_bounds__(256, 4) void nsf_fused_kernel(
    const float* __restrict__ x,
    const float* __restrict__ b1g, const float* __restrict__ b2g,
    const float* __restrict__ b3g, const float* __restrict__ b4s,
    const f16_t* __restrict__ wf,
    float* __restrict__ out) {
  __shared__ f16_t hH[MTILE * 136];       // hidden state, in-place across layers
  __shared__ f16_t prm[MTILE * 4 * 24];   // spline params chunk, f16 24-slots
  __shared__ float x2s[MTILE * 33];       // x2 tile, fp32

  const int tid = threadIdx.x;
  const int lane = tid & 63;
  const int wv = tid >> 6;
  const int l16 = lane & 15, lhi = lane >> 4;
  const int row0 = blockIdx.x * MTILE;

  // ---- stage x: x1 -> out + hH (f16), x2 -> x2s (f32) ----
  {
    const float4* x4 = (const float4*)(x + (size_t)row0 * 64);
    float4* o4 = (float4*)(out + (size_t)row0 * 64);
#pragma unroll
    for (int it = 0; it < 4; ++it) {
      int idx = tid + it * 256;          // 0..1023 = 64 rows x 16 float4
      int row = idx >> 4, q = idx & 15;
      float4 v = x4[row * 16 + q];
      if (q < 8) {                       // x1 cols 0..31
        o4[row * 16 + q] = v;
        f16x4 p = {(f16_t)v.x, (f16_t)v.y, (f16_t)v.z, (f16_t)v.w};
        *(f16x4*)&hH[row * 136 + q * 4] = p;
      } else {                           // x2 cols 32..63
        int cb = row * 33 + (q - 8) * 4;
        x2s[cb + 0] = v.x; x2s[cb + 1] = v.y;
        x2s[cb + 2] = v.z; x2s[cb + 3] = v.w;
      }
    }
  }
  __syncthreads();

  // ---- layer 1: (64x32)@(32x128), K=32, in-place ----
  {
    f16x8 a = *(const f16x8*)&hH[(wv * 16 + l16) * 136 + lhi * 8];
#pragma unroll
    for (int n = 0; n < 8; ++n) {
      f16x8 b = *(const f16x8*)(wf + W1F + (size_t)(n * 64 + lane) * 8);
      f32x4 acc = {0.f, 0.f, 0.f, 0.f};
      acc = __builtin_amdgcn_mfma_f32_16x16x32_f16(a, b, acc, 0, 0, 0);
      float bias = b1g[n * 16 + l16];
#pragma unroll
      for (int r = 0; r < 4; ++r)
        hH[(wv * 16 + lhi * 4 + r) * 136 + n * 16 + l16] =
            (f16_t)elu(acc[r] + bias);
    }
  }
  __syncthreads();

  mid_layer_ip(hH, wf + W2F, b2g, wv, l16, lhi, lane);   // layer 2
  __syncthreads();
  mid_layer_ip(hH, wf + W3F, b3g, wv, l16, lhi, lane);   // layer 3
  __syncthreads();

  // ---- layer 4 + spline, 8 chunks; wave-level sync only ----
  {
    f16x8 a4[4];
#pragma unroll
    for (int s = 0; s < 4; ++s)
      a4[s] = *(const f16x8*)&hH[(wv * 16 + l16) * 136 + s * 32 + lhi * 8];

    const int srow = tid >> 2;   // spline row 0..63 (== wave's own rows)
    const int sjj = tid & 3;     // chunk-local spline dim
    float ldp = 0.f;

    for (int c = 0; c < 8; ++c) {
      // GEMM4 chunk: 92 real cols (4 dims x 23) padded to 96 (6 tiles)
#pragma unroll
      for (int n = 0; n < 6; ++n) {
        f32x4 acc = {0.f, 0.f, 0.f, 0.f};
#pragma unroll
        for (int s = 0; s < 4; ++s) {
          f16x8 b = *(const f16x8*)(wf + W4F +
                      (size_t)(((c * 6 + n) * 4 + s) * 64 + lane) * 8);
          acc = __builtin_amdgcn_mfma_f32_16x16x32_f16(a4[s], b, acc, 0, 0, 0);
        }
        int colc = n * 16 + l16;
        if (colc < 92) {
          int dm = (colc * 90) >> 11;          // colc / 23 for colc < 92
          int j = colc - dm * 23;
          float bias = b4s[c * 92 + colc];
#pragma unroll
          for (int r = 0; r < 4; ++r)
            prm[((wv * 16 + lhi * 4 + r) * 4 + dm) * 24 + j] =
                (f16_t)(acc[r] + bias);
        }
      }
      __builtin_amdgcn_wave_barrier();     // writer==reader wave; order only

      // ---- spline: one (row, dim) task per thread (slot == tid) ----
      {
        int jg = c * 4 + sjj;
        float xv = x2s[srow * 33 + jg];
        float y0, l0;
        rqs_task(prm + tid * 24, xv, y0, l0);
        out[(size_t)(row0 + srow) * 64 + 32 + jg] = y0;
        ldp += l0;
      }
      __builtin_amdgcn_wave_barrier();     // WAR before next chunk's writes
    }

    // ---- log_det: quad reduce over sjj ----
    ldp += __shfl_xor(ldp, 1, 64);
    ldp += __shfl_xor(ldp, 2, 64);
    if ((tid & 3) == 0)
      out[(size_t)BATCH * 64 + row0 + srow] = ldp;
  }
}

// ---------------------------------------------------------------------------
extern "C" void kernel_launch(void* const* d_in, const int* in_sizes, int n_in,
                              void* d_out, int out_size, void* d_ws, size_t ws_size,
                              hipStream_t stream) {
  const float* x  = (const float*)d_in[0];
  const float* W1 = (const float*)d_in[1];
  const float* b1 = (const float*)d_in[2];
  const float* W2 = (const float*)d_in[3];
  const float* b2 = (const float*)d_in[4];
  const float* W3 = (const float*)d_in[5];
  const float* b3 = (const float*)d_in[6];
  const float* W4 = (const float*)d_in[7];
  const float* b4 = (const float*)d_in[8];
  f16_t* wf = (f16_t*)d_ws;
  float* b4s = (float*)d_ws + B4S_OFF;
  float* out = (float*)d_out;

  hipLaunchKernelGGL(convert_weights_kernel, dim3(69), dim3(256), 0, stream,
                     W1, W2, W3, W4, b4, wf, b4s);
  hipLaunchKernelGGL(nsf_fused_kernel, dim3(NBLK), dim3(256), 0, stream,
                     x, b1, b2, b3, b4s, wf, out);
}